// Round 8
// baseline (243.733 us; speedup 1.0000x reference)
//
#include <hip/hip_runtime.h>

#define BB   4
#define NHID 128
#define LL   1024
#define NH   10
#define HD   10
#define DD   100
#define SCALE 0.31622776601683794f   // 1/sqrt(10)

typedef float vfloat4 __attribute__((ext_vector_type(4)));

// ---- K1 (fused prep): blk<4096 -> packmask; else qproj(10ch/head)+esj ----
// packmask: pm[row*32 + m*8 + g], nibble (lane&7)*4 = edge j=m*256+lane*4+{0..3}
__global__ __launch_bounds__(256) void k_prep(
    const int* __restrict__ edge, const float* __restrict__ x,
    const float* __restrict__ wq_w, const float* __restrict__ wq_b,
    const float* __restrict__ we_w,
    unsigned* __restrict__ pm, float* __restrict__ kT, float* __restrict__ esj) {
  const int blk = blockIdx.x;
  if (blk < BB * LL) {                       // ---- packmask ----
    const int row  = blk;
    const int lane = threadIdx.x & 63;
    const int m    = threadIdx.x >> 6;
    int4 e = ((const int4*)(edge + (size_t)row * LL))[m * 64 + lane];
    unsigned v = ((e.x ? 1u : 0u) | (e.y ? 2u : 0u) | (e.z ? 4u : 0u) | (e.w ? 8u : 0u))
                 << ((lane & 7) * 4);
    v |= __shfl_xor(v, 1, 64);
    v |= __shfl_xor(v, 2, 64);
    v |= __shfl_xor(v, 4, 64);
    if ((lane & 7) == 0)
      pm[row * 32 + m * 8 + (lane >> 3)] = v;
    return;
  }
  // ---- qproj: one head (10 channels) per block + esj inline ----
  const int idx = blk - BB * LL;             // 0..159
  const int b   = idx / (NH * 4);
  const int rem = idx % (NH * 4);
  const int n   = rem >> 2;
  const int l   = (rem & 3) * 256 + threadIdx.x;
  float acc[HD];
  #pragma unroll
  for (int d = 0; d < HD; ++d) acc[d] = wq_b[n * HD + d];
  const float* xb = x + (size_t)b * NHID * LL + l;
  const float* w0 = wq_w + (size_t)(n * HD) * NHID;
  #pragma unroll 4
  for (int h = 0; h < NHID; ++h) {
    float xv = xb[(size_t)h * LL];           // coalesced
    #pragma unroll
    for (int d = 0; d < HD; ++d) acc[d] += w0[d * NHID + h] * xv;  // scalar loads
  }
  const int bn = b * NH + n;
  float s2 = 0.f;
  #pragma unroll
  for (int d = 0; d < HD; ++d) {
    kT[(((size_t)bn) * HD + d) * LL + l] = acc[d];   // coalesced
    s2 += acc[d] * we_w[HD + d];
  }
  esj[(size_t)bn * LL + l] = __expf(s2 * SCALE);
}

// ---- K2: fused mask+softmax+PV; denom pre-pass, stores interleaved w/ FMA --
// alpha[i,j] = mask[i,j]*esj[j] / sum_j mask[i,j]*esj[j]
// block = 256 (4 waves), 4 rows/wave -> 16 rows/block; grid (64, B*NH).
__global__ __launch_bounds__(256) void k_attn(
    const float* __restrict__ kT, const float* __restrict__ esj,
    const unsigned* __restrict__ pm,
    float* __restrict__ alpha_out, float* __restrict__ att) {
  const int t    = threadIdx.x;
  const int lane = t & 63;
  const int wid  = t >> 6;
  const int bn   = blockIdx.y;
  const int b    = bn / NH;
  const int i0   = blockIdx.x * 16 + wid * 4;

  __shared__ float ksT[HD * LL];    // 40 KB: kT[b,n,:,:] (d-major, stride-1 in j)
  {
    const float4* src = (const float4*)(kT + (size_t)bn * (HD * LL));
    float4* dst = (float4*)ksT;
    #pragma unroll
    for (int idx = t; idx < (HD * LL) / 4; idx += 256) dst[idx] = src[idx];
  }
  vfloat4 esv[4];                   // esj, j = m*256 + lane*4 + q
  {
    const vfloat4* sp = (const vfloat4*)(esj + (size_t)bn * LL);
    #pragma unroll
    for (int m = 0; m < 4; ++m) esv[m] = sp[m * 64 + lane];
  }
  // masks compressed to 16 bits/row: bit (m*4+q) = edge(i0+r, m*256+lane*4+q)
  const int s4 = (lane & 7) * 4;
  unsigned mask[4] = {0u, 0u, 0u, 0u};
  #pragma unroll
  for (int r = 0; r < 4; ++r) {
    const unsigned* pmrow = pm + ((size_t)b * LL + (i0 + r)) * 32 + (lane >> 3);
    #pragma unroll
    for (int m = 0; m < 4; ++m)
      mask[r] |= ((pmrow[m * 8] >> s4) & 0xFu) << (m * 4);
  }
  // ---- denom pre-pass (no k needed) -> inv before main loop ----
  float inv[4];
  #pragma unroll
  for (int r = 0; r < 4; ++r) {
    float s = 0.f;
    #pragma unroll
    for (int m = 0; m < 4; ++m) {
      const unsigned mk = mask[r] >> (m * 4);
      s += ((mk & 1u) ? esv[m].x : 0.f) + ((mk & 2u) ? esv[m].y : 0.f)
         + ((mk & 4u) ? esv[m].z : 0.f) + ((mk & 8u) ? esv[m].w : 0.f);
    }
    #pragma unroll
    for (int sft = 32; sft >= 1; sft >>= 1) s += __shfl_xor(s, sft, 64);
    inv[r] = __builtin_amdgcn_rcpf(s);
  }
  __syncthreads();

  // ---- main loop: alpha compute+store interleaved with PV FMA ----
  float part[4][HD];
  #pragma unroll
  for (int r = 0; r < 4; ++r)
    #pragma unroll
    for (int d = 0; d < HD; ++d) part[r][d] = 0.f;

  float* ap = alpha_out + ((size_t)bn * LL + i0) * LL;
  #pragma unroll
  for (int m = 0; m < 4; ++m) {
    const float* kb = ksT + m * 256 + lane * 4;
    vfloat4 kv[5];
    #pragma unroll
    for (int d = 0; d < 5; ++d) kv[d] = *(const vfloat4*)(kb + d * LL);  // b128, conflict-free
    #pragma unroll
    for (int r = 0; r < 4; ++r) {
      const unsigned mk = mask[r] >> (m * 4);
      vfloat4 a;                               // normalized alpha
      a.x = (mk & 1u) ? esv[m].x * inv[r] : 0.f;
      a.y = (mk & 2u) ? esv[m].y * inv[r] : 0.f;
      a.z = (mk & 4u) ? esv[m].z * inv[r] : 0.f;
      a.w = (mk & 8u) ? esv[m].w * inv[r] : 0.f;
      *((vfloat4*)(ap + (size_t)r * LL) + m * 64 + lane) = a;   // store amid FMA
      #pragma unroll
      for (int d = 0; d < 5; ++d)
        part[r][d] += a.x * kv[d].x + a.y * kv[d].y + a.z * kv[d].z + a.w * kv[d].w;
    }
    #pragma unroll
    for (int d = 0; d < 5; ++d) kv[d] = *(const vfloat4*)(kb + (d + 5) * LL);
    #pragma unroll
    for (int r = 0; r < 4; ++r) {
      const unsigned mk = mask[r] >> (m * 4);
      vfloat4 a;                               // recompute (cheap, saves regs)
      a.x = (mk & 1u) ? esv[m].x * inv[r] : 0.f;
      a.y = (mk & 2u) ? esv[m].y * inv[r] : 0.f;
      a.z = (mk & 4u) ? esv[m].z * inv[r] : 0.f;
      a.w = (mk & 8u) ? esv[m].w * inv[r] : 0.f;
      #pragma unroll
      for (int d = 0; d < 5; ++d)
        part[r][d + 5] += a.x * kv[d].x + a.y * kv[d].y + a.z * kv[d].z + a.w * kv[d].w;
    }
  }

  // ---- PV reduce-scatter (part already normalized): 17 shuffles/row ----
  const bool c5 = (lane & 32) != 0;
  const bool c4 = (lane & 16) != 0;
  const bool c3 = (lane & 8) != 0;
  const bool c2 = (lane & 4) != 0;
  #pragma unroll
  for (int r = 0; r < 4; ++r) {
    float pv[16];
    #pragma unroll
    for (int d = 0; d < HD; ++d) pv[d] = part[r][d];
    #pragma unroll
    for (int d = HD; d < 16; ++d) pv[d] = 0.f;
    #pragma unroll
    for (int i = 0; i < 8; ++i) {
      float snd = c5 ? pv[i] : pv[i + 8];
      float kp  = c5 ? pv[i + 8] : pv[i];
      pv[i] = kp + __shfl_xor(snd, 32, 64);
    }
    #pragma unroll
    for (int i = 0; i < 4; ++i) {
      float snd = c4 ? pv[i] : pv[i + 4];
      float kp  = c4 ? pv[i + 4] : pv[i];
      pv[i] = kp + __shfl_xor(snd, 16, 64);
    }
    #pragma unroll
    for (int i = 0; i < 2; ++i) {
      float snd = c3 ? pv[i] : pv[i + 2];
      float kp  = c3 ? pv[i + 2] : pv[i];
      pv[i] = kp + __shfl_xor(snd, 8, 64);
    }
    {
      float snd = c2 ? pv[0] : pv[1];
      float kp  = c2 ? pv[1] : pv[0];
      pv[0] = kp + __shfl_xor(snd, 4, 64);
    }
    pv[0] += __shfl_xor(pv[0], 2, 64);
    pv[0] += __shfl_xor(pv[0], 1, 64);
    float g = __shfl(pv[0], lane * 4, 64);   // lane l holds d=(l>>2)&15
    if (lane < HD)
      att[((size_t)bn * LL + (i0 + r)) * HD + lane] = g;
  }
}

// ---------------- K3: output projection over scrambled view ----------------
__global__ __launch_bounds__(256) void k_out(
    const float* __restrict__ att, const float* __restrict__ wo_w,
    const float* __restrict__ wo_b, float* __restrict__ ret) {
  const int l  = blockIdx.x * 256 + threadIdx.x;
  const int o0 = blockIdx.y * 4;
  const int b  = blockIdx.z;
  const float* ab = att + (size_t)b * (DD * LL);
  float acc[4];
  #pragma unroll
  for (int oo = 0; oo < 4; ++oo) acc[oo] = wo_b[o0 + oo];
  for (int c = 0; c < DD; ++c) {
    float a = ab[(size_t)c * LL + l];          // coalesced; view(B,-1,L) == linear index
    #pragma unroll
    for (int oo = 0; oo < 4; ++oo) acc[oo] += wo_w[(size_t)(o0 + oo) * DD + c] * a;
  }
  #pragma unroll
  for (int oo = 0; oo < 4; ++oo)
    ret[((size_t)b * NHID + o0 + oo) * LL + l] = acc[oo];
}

extern "C" void kernel_launch(void* const* d_in, const int* in_sizes, int n_in,
                              void* d_out, int out_size, void* d_ws, size_t ws_size,
                              hipStream_t stream) {
  (void)in_sizes; (void)n_in; (void)out_size; (void)ws_size;
  const float* x    = (const float*)d_in[0];
  const int*   edge = (const int*)d_in[1];
  const float* wq_w = (const float*)d_in[2];
  const float* wq_b = (const float*)d_in[3];
  const float* we_w = (const float*)d_in[4];
  const float* wo_w = (const float*)d_in[6];
  const float* wo_b = (const float*)d_in[7];

  float* out       = (float*)d_out;
  float* ret_out   = out;                                  // B*NHID*L
  float* alpha_out = out + (size_t)BB * NHID * LL;         // B*NH*L*L

  float* ws   = (float*)d_ws;
  float* kT   = ws;                                        // B*NH*HD*L = 409600
  float* esj  = kT + (size_t)BB * NH * HD * LL;            // B*NH*L
  float* att  = esj + (size_t)BB * NH * LL;                // B*NH*L*HD
  unsigned* pmask = (unsigned*)(att + (size_t)BB * NH * LL * HD);  // B*L*32 uints

  k_prep<<<BB * LL + BB * NH * 4, 256, 0, stream>>>(
      edge, x, wq_w, wq_b, we_w, pmask, kT, esj);

  dim3 g2(LL / 16, BB * NH);
  k_attn<<<g2, 256, 0, stream>>>(kT, esj, pmask, alpha_out, att);

  dim3 g3(LL / 256, NHID / 4, BB);
  k_out<<<g3, 256, 0, stream>>>(att, wo_w, wo_b, ret_out);
}